// Round 9
// baseline (46.644 us; speedup 1.0000x reference)
//
#include <hip/hip_runtime.h>
#include <hip/hip_fp16.h>

#define NG 14
#define NE 16
#define NW 32            // wafers per chunk/block
#define YW 148           // per-wafer y stride in LDS (half units); odd granule -> bank spread

__device__ __forceinline__ float d4(float4 a, float4 b) {
    return a.x*b.x + a.y*b.y + a.z*b.z + a.w*b.w;
}

// load 4 consecutive halfs -> float4 (8B-aligned ds_read_b64)
__device__ __forceinline__ float4 ld4h(const __half* p) {
    const __half2 a = *(const __half2*)(p);
    const __half2 b = *(const __half2*)(p + 2);
    const float2 fa = __half22float2(a), fb = __half22float2(b);
    return make_float4(fa.x, fa.y, fb.x, fb.y);
}

__global__ __launch_bounds__(1024) void bin_kernel(const int* __restrict__ keys, int N,
                                                   int NBW, int* __restrict__ sorted) {
    __shared__ int hist[NE], offs[NE], cur[NE];
    const int t = threadIdx.x;
    if (t < NE) { hist[t] = 0; cur[t] = 0; }
    for (int i = t; i < NBW; i += 1024) sorted[i] = -1;
    __syncthreads();
    for (int i = t; i < N; i += 1024) atomicAdd(&hist[keys[i]], 1);
    __syncthreads();
    if (t == 0) {
        int run = 0;
        for (int e = 0; e < NE; ++e) { offs[e] = run; run += (hist[e] + NW - 1) & ~(NW - 1); }
    }
    __syncthreads();
    for (int i = t; i < N; i += 1024) {
        const int e = keys[i];
        sorted[offs[e] + atomicAdd(&cur[e], 1)] = i;
    }
}

// compile-time-folded zero-padded x access
#define XEL(R,C) (((R) < 0 || (R) > 7 || (C) < 0 || (C) > 7) ? 0.f : xv[(R)&7][(C)&7])

__global__ __launch_bounds__(256, 8) void ae_main(
    const float* __restrict__ x,
    const int*   __restrict__ keys,
    const float* __restrict__ conv_mask,
    const float* __restrict__ enc_conv_w,
    const float* __restrict__ enc_dense_w,
    const float* __restrict__ enc_dense_b,
    const float* __restrict__ dec_dense_w,
    const float* __restrict__ dec_dense_b,
    const float* __restrict__ dec_tconv_w,
    const float* __restrict__ dec_tconv_b,
    const int*   __restrict__ sorted,
    float* __restrict__ out)
{
    const int t = threadIdx.x;
    const int chunk = blockIdx.x / NG;
    const int g = blockIdx.x - chunk * NG;

    __shared__ __attribute__((aligned(16))) __half yt[NW * YW]; // y in fp16 (9.5 KB)
    __shared__ __attribute__((aligned(16))) float ews[1024];    // enc dense w swizzled
    __shared__ __attribute__((aligned(16))) float dws[1024];    // dec dense w swizzled
    __shared__ __attribute__((aligned(16))) float wcs[72];      // masked conv w [tap*8+ch]
    __shared__ __attribute__((aligned(16))) float wtr[96];      // tconv w [tap*8+ch], taps 9..11 = 0
    __shared__ float dbs[128];                                  // dec bias [p*8+ch]
    __shared__ float ebs[8];

    const int* chunkIds = sorted + chunk * NW;
    const int i0 = chunkIds[0];
    if (i0 < 0) return;
    const int k = keys[i0];

    const int w = t >> 3, ch = t & 7;
    const int idw = chunkIds[w];
    const int idr = (idw < 0) ? i0 : idw;

    // ---- x rows -> registers: 16 independent loads issued before staging ----
    const float* xg = x + (size_t)idr * 896 + g * 64;
    float xv[8][8];
    #pragma unroll
    for (int r = 0; r < 8; ++r) {
        const float4 a = *(const float4*)(xg + r * 8);
        const float4 b = *(const float4*)(xg + r * 8 + 4);
        xv[r][0]=a.x; xv[r][1]=a.y; xv[r][2]=a.z; xv[r][3]=a.w;
        xv[r][4]=b.x; xv[r][5]=b.y; xv[r][6]=b.z; xv[r][7]=b.w;
    }

    // ---- stage all per-(expert,group) weights into LDS (coalesced) ----
    const size_t wg1024 = (size_t)(k * NG + g) * 1024;
    for (int i = t; i < 1024; i += 256) {
        const int o = i >> 7, rem = i & 127, c2 = rem >> 4, r2 = rem & 15;
        ews[(((o << 2) | (r2 >> 2)) * 8 + c2) * 4 + (r2 & 3)] = enc_dense_w[wg1024 + i];
    }
    for (int i = t; i < 1024; i += 256) {
        const int c2 = i >> 7, rem = i & 127;
        dws[(rem >> 3) * 64 + c2 * 8 + (rem & 7)] = dec_dense_w[wg1024 + i];
    }
    if (t < 128) {
        dbs[(t & 15) * 8 + (t >> 4)] = dec_dense_b[(size_t)k * 1792 + g * 128 + t];
    } else if (t < 200) {
        const int i = t - 128, c2 = i / 9, tap = i - c2 * 9;
        wcs[tap * 8 + c2] = enc_conv_w[(size_t)k * 1008 + (g * 8 + c2) * 9 + tap] * conv_mask[tap];
    } else if (t < 208) {
        ebs[t - 200] = enc_dense_b[(size_t)k * 112 + g * 8 + (t - 200)];
    }
    if (t < 96) {
        const int tap = t >> 3, c2 = t & 7;
        wtr[t] = (tap < 9) ? dec_tconv_w[(size_t)k * 1008 + (g * 8 + c2) * 9 + tap] : 0.f;
    }
    __syncthreads();

    // ---- P1+P2 fused: conv(7 taps)+ReLU+maxpool -> enc GEMV partials ----
    const float w0 = wcs[0*8+ch], w1 = wcs[1*8+ch], w3 = wcs[3*8+ch], w4 = wcs[4*8+ch],
                w5 = wcs[5*8+ch], w7 = wcs[7*8+ch], w8 = wcs[8*8+ch];
    float part[8] = {0.f,0.f,0.f,0.f,0.f,0.f,0.f,0.f};
    #pragma unroll
    for (int pr = 0; pr < 4; ++pr) {
        float res[4];
        #pragma unroll
        for (int pc = 0; pc < 4; ++pc) {
            float mx = 0.f;
            #pragma unroll
            for (int rl = 0; rl < 2; ++rl) {
                #pragma unroll
                for (int cl = 0; cl < 2; ++cl) {
                    const int ir = 2*pr + rl, jc = 2*pc + cl;
                    const float s = w0*XEL(ir-1,jc-1) + w1*XEL(ir-1,jc)
                                  + w3*XEL(ir,jc-1)  + w4*XEL(ir,jc) + w5*XEL(ir,jc+1)
                                  + w7*XEL(ir+1,jc)  + w8*XEL(ir+1,jc+1);
                    mx = fmaxf(mx, s);
                }
            }
            res[pc] = mx;
        }
        #pragma unroll
        for (int o = 0; o < 8; ++o) {
            const float4 we = *(const float4*)(ews + (((o << 2) | pr) * 8 + ch) * 4);
            part[o] += we.x*res[0] + we.y*res[1] + we.z*res[2] + we.w*res[3];
        }
    }

    // ---- reduce across the 8 channel lanes; z in registers ----
    float z[8];
    #pragma unroll
    for (int o = 0; o < 8; ++o) {
        float v = part[o];
        v += __shfl_xor(v, 1);
        v += __shfl_xor(v, 2);
        v += __shfl_xor(v, 4);
        z[o] = fmaxf(v + ebs[o], 0.f);
    }

    // ---- P3: y = relu(decW . z + b) -> LDS fp16 [w][pi*36+pj*8+ch] ----
    __half* yw_ = yt + w * YW;
    #pragma unroll
    for (int p = 0; p < 16; ++p) {
        const float4 wa = *(const float4*)(dws + p * 64 + ch * 8);
        const float4 wb = *(const float4*)(dws + p * 64 + ch * 8 + 4);
        const float v = dbs[p * 8 + ch]
            + wa.x*z[0] + wa.y*z[1] + wa.z*z[2] + wa.w*z[3]
            + wb.x*z[4] + wb.y*z[5] + wb.z*z[6] + wb.w*z[7];
        yw_[(p >> 2) * 36 + (p & 3) * 8 + ch] = __float2half(fmaxf(v, 0.f));
    }
    __syncthreads();

    // ---- P4: ConvTranspose2d(stride2,pad1,outpad1); thread (w, oi=ch) -> one row ----
    const int oi = ch;
    int iA, rA, iB, rB;
    if ((oi & 1) == 0) { iA = oi >> 1; rA = 3; iB = 0; rB = 9; }
    else { iA = (oi - 1) >> 1; rA = 6;
           if (oi < 7) { iB = (oi + 1) >> 1; rB = 0; } else { iB = 0; rB = 9; } }
    const float bias = dec_tconv_b[k * NG + g];
    float acc[8] = {0.f,0.f,0.f,0.f,0.f,0.f,0.f,0.f};
    #pragma unroll
    for (int hc = 0; hc < 2; ++hc) {
        const float4 wA0 = *(const float4*)(wtr + (rA + 0) * 8 + hc * 4);
        const float4 wA1 = *(const float4*)(wtr + (rA + 1) * 8 + hc * 4);
        const float4 wA2 = *(const float4*)(wtr + (rA + 2) * 8 + hc * 4);
        const float4 wB0 = *(const float4*)(wtr + (rB + 0) * 8 + hc * 4);
        const float4 wB1 = *(const float4*)(wtr + (rB + 1) * 8 + hc * 4);
        const float4 wB2 = *(const float4*)(wtr + (rB + 2) * 8 + hc * 4);
        float4 yA[4], yB[4];
        #pragma unroll
        for (int j = 0; j < 4; ++j) {
            yA[j] = ld4h(yw_ + iA * 36 + j * 8 + hc * 4);
            yB[j] = ld4h(yw_ + iB * 36 + j * 8 + hc * 4);
        }
        acc[0] += d4(wA1,yA[0]) + d4(wB1,yB[0]);
        acc[1] += d4(wA2,yA[0]) + d4(wA0,yA[1]) + d4(wB2,yB[0]) + d4(wB0,yB[1]);
        acc[2] += d4(wA1,yA[1]) + d4(wB1,yB[1]);
        acc[3] += d4(wA2,yA[1]) + d4(wA0,yA[2]) + d4(wB2,yB[1]) + d4(wB0,yB[2]);
        acc[4] += d4(wA1,yA[2]) + d4(wB1,yB[2]);
        acc[5] += d4(wA2,yA[2]) + d4(wA0,yA[3]) + d4(wB2,yB[2]) + d4(wB0,yB[3]);
        acc[6] += d4(wA1,yA[3]) + d4(wB1,yB[3]);
        acc[7] += d4(wA2,yA[3]) + d4(wB2,yB[3]);
    }
    if (idw >= 0) {
        float* og = out + (size_t)idw * 896 + g * 64 + oi * 8;
        *(float4*)(og)     = make_float4(fmaxf(acc[0]+bias,0.f), fmaxf(acc[1]+bias,0.f),
                                         fmaxf(acc[2]+bias,0.f), fmaxf(acc[3]+bias,0.f));
        *(float4*)(og + 4) = make_float4(fmaxf(acc[4]+bias,0.f), fmaxf(acc[5]+bias,0.f),
                                         fmaxf(acc[6]+bias,0.f), fmaxf(acc[7]+bias,0.f));
    }
}

extern "C" void kernel_launch(void* const* d_in, const int* in_sizes, int n_in,
                              void* d_out, int out_size, void* d_ws, size_t ws_size,
                              hipStream_t stream) {
    const float* x            = (const float*)d_in[0];
    const int*   keys         = (const int*)d_in[1];
    const float* conv_mask    = (const float*)d_in[2];
    const float* enc_conv_w   = (const float*)d_in[3];
    const float* enc_dense_w  = (const float*)d_in[4];
    const float* enc_dense_b  = (const float*)d_in[5];
    const float* dec_dense_w  = (const float*)d_in[6];
    const float* dec_dense_b  = (const float*)d_in[7];
    const float* dec_tconv_w  = (const float*)d_in[8];
    const float* dec_tconv_b  = (const float*)d_in[9];
    float* out = (float*)d_out;

    const int N = in_sizes[0] / (NG * 64);                   // 4096
    const int CHUNKS = (N + NE * (NW - 1)) / NW + 1;         // 144
    int* sorted = (int*)d_ws;

    bin_kernel<<<1, 1024, 0, stream>>>(keys, N, CHUNKS * NW, sorted);
    ae_main<<<CHUNKS * NG, 256, 0, stream>>>(
        x, keys, conv_mask, enc_conv_w, enc_dense_w, enc_dense_b,
        dec_dense_w, dec_dense_b, dec_tconv_w, dec_tconv_b, sorted, out);
}

// Round 10
// 30.898 us; speedup vs baseline: 1.5096x; 1.5096x over previous
//
#include <hip/hip_runtime.h>
#include <hip/hip_fp16.h>

#define NG 14
#define NE 16
#define NW 32            // wafers per chunk/block
#define YW 148           // per-wafer y stride in LDS (half units)

__device__ __forceinline__ float d4(float4 a, float4 b) {
    return a.x*b.x + a.y*b.y + a.z*b.z + a.w*b.w;
}

// load 4 consecutive halfs -> float4 (8B-aligned ds_read_b64)
__device__ __forceinline__ float4 ld4h(const __half* p) {
    const __half2 a = *(const __half2*)(p);
    const __half2 b = *(const __half2*)(p + 2);
    const float2 fa = __half22float2(a), fb = __half22float2(b);
    return make_float4(fa.x, fa.y, fb.x, fb.y);
}

__global__ __launch_bounds__(1024) void bin_kernel(const int* __restrict__ keys, int N,
                                                   int NBW, int* __restrict__ sorted) {
    __shared__ int hist[NE], offs[NE], cur[NE];
    const int t = threadIdx.x;
    if (t < NE) { hist[t] = 0; cur[t] = 0; }
    for (int i = t; i < NBW; i += 1024) sorted[i] = -1;
    __syncthreads();
    for (int i = t; i < N; i += 1024) atomicAdd(&hist[keys[i]], 1);
    __syncthreads();
    if (t == 0) {
        int run = 0;
        for (int e = 0; e < NE; ++e) { offs[e] = run; run += (hist[e] + NW - 1) & ~(NW - 1); }
    }
    __syncthreads();
    for (int i = t; i < N; i += 1024) {
        const int e = keys[i];
        sorted[offs[e] + atomicAdd(&cur[e], 1)] = i;
    }
}

// compile-time-folded zero-padded x access
#define XEL(R,C) (((R) < 0 || (R) > 7 || (C) < 0 || (C) > 7) ? 0.f : xv[(R)&7][(C)&7])

__global__ __launch_bounds__(256, 4) void ae_main(
    const float* __restrict__ x,
    const int*   __restrict__ keys,
    const float* __restrict__ conv_mask,
    const float* __restrict__ enc_conv_w,
    const float* __restrict__ enc_dense_w,
    const float* __restrict__ enc_dense_b,
    const float* __restrict__ dec_dense_w,
    const float* __restrict__ dec_dense_b,
    const float* __restrict__ dec_tconv_w,
    const float* __restrict__ dec_tconv_b,
    const int*   __restrict__ sorted,
    float* __restrict__ out)
{
    const int t = threadIdx.x;
    const int chunk = blockIdx.x / NG;
    const int g = blockIdx.x - chunk * NG;

    __shared__ __attribute__((aligned(16))) __half yt[NW * YW]; // y in fp16 (9.5 KB)
    __shared__ __attribute__((aligned(16))) float ews[1024];    // enc dense w swizzled
    __shared__ __attribute__((aligned(16))) float dws[1024];    // dec dense w swizzled
    __shared__ __attribute__((aligned(16))) float wcs[72];      // masked conv w [tap*8+ch]
    __shared__ __attribute__((aligned(16))) float wtr[96];      // tconv w [tap*8+ch], taps 9..11 = 0
    __shared__ float dbs[128];                                  // dec bias [p*8+ch]
    __shared__ float ebs[8];

    const int* chunkIds = sorted + chunk * NW;
    const int i0 = chunkIds[0];
    if (i0 < 0) return;
    const int k = keys[i0];

    const int w = t >> 3, ch = t & 7;
    const int idw = chunkIds[w];
    const int idr = (idw < 0) ? i0 : idw;

    // ---- x rows -> registers: 16 independent loads issued before staging ----
    const float* xg = x + (size_t)idr * 896 + g * 64;
    float xv[8][8];
    #pragma unroll
    for (int r = 0; r < 8; ++r) {
        const float4 a = *(const float4*)(xg + r * 8);
        const float4 b = *(const float4*)(xg + r * 8 + 4);
        xv[r][0]=a.x; xv[r][1]=a.y; xv[r][2]=a.z; xv[r][3]=a.w;
        xv[r][4]=b.x; xv[r][5]=b.y; xv[r][6]=b.z; xv[r][7]=b.w;
    }

    // ---- stage all per-(expert,group) weights into LDS (coalesced) ----
    const size_t wg1024 = (size_t)(k * NG + g) * 1024;
    for (int i = t; i < 1024; i += 256) {
        const int o = i >> 7, rem = i & 127, c2 = rem >> 4, r2 = rem & 15;
        ews[(((o << 2) | (r2 >> 2)) * 8 + c2) * 4 + (r2 & 3)] = enc_dense_w[wg1024 + i];
    }
    for (int i = t; i < 1024; i += 256) {
        const int c2 = i >> 7, rem = i & 127;
        dws[(rem >> 3) * 64 + c2 * 8 + (rem & 7)] = dec_dense_w[wg1024 + i];
    }
    if (t < 128) {
        dbs[(t & 15) * 8 + (t >> 4)] = dec_dense_b[(size_t)k * 1792 + g * 128 + t];
    } else if (t < 200) {
        const int i = t - 128, c2 = i / 9, tap = i - c2 * 9;
        wcs[tap * 8 + c2] = enc_conv_w[(size_t)k * 1008 + (g * 8 + c2) * 9 + tap] * conv_mask[tap];
    } else if (t < 208) {
        ebs[t - 200] = enc_dense_b[(size_t)k * 112 + g * 8 + (t - 200)];
    }
    if (t < 96) {
        const int tap = t >> 3, c2 = t & 7;
        wtr[t] = (tap < 9) ? dec_tconv_w[(size_t)k * 1008 + (g * 8 + c2) * 9 + tap] : 0.f;
    }
    __syncthreads();

    // ---- P1+P2 fused: conv(7 taps)+ReLU+maxpool -> enc GEMV partials ----
    const float w0 = wcs[0*8+ch], w1 = wcs[1*8+ch], w3 = wcs[3*8+ch], w4 = wcs[4*8+ch],
                w5 = wcs[5*8+ch], w7 = wcs[7*8+ch], w8 = wcs[8*8+ch];
    float part[8] = {0.f,0.f,0.f,0.f,0.f,0.f,0.f,0.f};
    #pragma unroll
    for (int pr = 0; pr < 4; ++pr) {
        float res[4];
        #pragma unroll
        for (int pc = 0; pc < 4; ++pc) {
            float mx = 0.f;
            #pragma unroll
            for (int rl = 0; rl < 2; ++rl) {
                #pragma unroll
                for (int cl = 0; cl < 2; ++cl) {
                    const int ir = 2*pr + rl, jc = 2*pc + cl;
                    const float s = w0*XEL(ir-1,jc-1) + w1*XEL(ir-1,jc)
                                  + w3*XEL(ir,jc-1)  + w4*XEL(ir,jc) + w5*XEL(ir,jc+1)
                                  + w7*XEL(ir+1,jc)  + w8*XEL(ir+1,jc+1);
                    mx = fmaxf(mx, s);
                }
            }
            res[pc] = mx;
        }
        #pragma unroll
        for (int o = 0; o < 8; ++o) {
            const float4 we = *(const float4*)(ews + (((o << 2) | pr) * 8 + ch) * 4);
            part[o] += we.x*res[0] + we.y*res[1] + we.z*res[2] + we.w*res[3];
        }
    }

    // ---- reduce across the 8 channel lanes; z in registers ----
    float z[8];
    #pragma unroll
    for (int o = 0; o < 8; ++o) {
        float v = part[o];
        v += __shfl_xor(v, 1);
        v += __shfl_xor(v, 2);
        v += __shfl_xor(v, 4);
        z[o] = fmaxf(v + ebs[o], 0.f);
    }

    // ---- P3: y = relu(decW . z + b) -> LDS fp16 [w][pi*36+pj*8+ch] ----
    __half* yw_ = yt + w * YW;
    #pragma unroll
    for (int p = 0; p < 16; ++p) {
        const float4 wa = *(const float4*)(dws + p * 64 + ch * 8);
        const float4 wb = *(const float4*)(dws + p * 64 + ch * 8 + 4);
        const float v = dbs[p * 8 + ch]
            + wa.x*z[0] + wa.y*z[1] + wa.z*z[2] + wa.w*z[3]
            + wb.x*z[4] + wb.y*z[5] + wb.z*z[6] + wb.w*z[7];
        yw_[(p >> 2) * 36 + (p & 3) * 8 + ch] = __float2half(fmaxf(v, 0.f));
    }
    __syncthreads();

    // ---- P4: ConvTranspose2d(stride2,pad1,outpad1); thread (w, oi=ch) -> one row ----
    const int oi = ch;
    int iA, rA, iB, rB;
    if ((oi & 1) == 0) { iA = oi >> 1; rA = 3; iB = 0; rB = 9; }
    else { iA = (oi - 1) >> 1; rA = 6;
           if (oi < 7) { iB = (oi + 1) >> 1; rB = 0; } else { iB = 0; rB = 9; } }
    const float bias = dec_tconv_b[k * NG + g];
    float acc[8] = {0.f,0.f,0.f,0.f,0.f,0.f,0.f,0.f};
    #pragma unroll
    for (int hc = 0; hc < 2; ++hc) {
        const float4 wA0 = *(const float4*)(wtr + (rA + 0) * 8 + hc * 4);
        const float4 wA1 = *(const float4*)(wtr + (rA + 1) * 8 + hc * 4);
        const float4 wA2 = *(const float4*)(wtr + (rA + 2) * 8 + hc * 4);
        const float4 wB0 = *(const float4*)(wtr + (rB + 0) * 8 + hc * 4);
        const float4 wB1 = *(const float4*)(wtr + (rB + 1) * 8 + hc * 4);
        const float4 wB2 = *(const float4*)(wtr + (rB + 2) * 8 + hc * 4);
        float4 yA[4], yB[4];
        #pragma unroll
        for (int j = 0; j < 4; ++j) {
            yA[j] = ld4h(yw_ + iA * 36 + j * 8 + hc * 4);
            yB[j] = ld4h(yw_ + iB * 36 + j * 8 + hc * 4);
        }
        acc[0] += d4(wA1,yA[0]) + d4(wB1,yB[0]);
        acc[1] += d4(wA2,yA[0]) + d4(wA0,yA[1]) + d4(wB2,yB[0]) + d4(wB0,yB[1]);
        acc[2] += d4(wA1,yA[1]) + d4(wB1,yB[1]);
        acc[3] += d4(wA2,yA[1]) + d4(wA0,yA[2]) + d4(wB2,yB[1]) + d4(wB0,yB[2]);
        acc[4] += d4(wA1,yA[2]) + d4(wB1,yB[2]);
        acc[5] += d4(wA2,yA[2]) + d4(wA0,yA[3]) + d4(wB2,yB[2]) + d4(wB0,yB[3]);
        acc[6] += d4(wA1,yA[3]) + d4(wB1,yB[3]);
        acc[7] += d4(wA2,yA[3]) + d4(wB2,yB[3]);
    }
    if (idw >= 0) {
        float* og = out + (size_t)idw * 896 + g * 64 + oi * 8;
        *(float4*)(og)     = make_float4(fmaxf(acc[0]+bias,0.f), fmaxf(acc[1]+bias,0.f),
                                         fmaxf(acc[2]+bias,0.f), fmaxf(acc[3]+bias,0.f));
        *(float4*)(og + 4) = make_float4(fmaxf(acc[4]+bias,0.f), fmaxf(acc[5]+bias,0.f),
                                         fmaxf(acc[6]+bias,0.f), fmaxf(acc[7]+bias,0.f));
    }
}

extern "C" void kernel_launch(void* const* d_in, const int* in_sizes, int n_in,
                              void* d_out, int out_size, void* d_ws, size_t ws_size,
                              hipStream_t stream) {
    const float* x            = (const float*)d_in[0];
    const int*   keys         = (const int*)d_in[1];
    const float* conv_mask    = (const float*)d_in[2];
    const float* enc_conv_w   = (const float*)d_in[3];
    const float* enc_dense_w  = (const float*)d_in[4];
    const float* enc_dense_b  = (const float*)d_in[5];
    const float* dec_dense_w  = (const float*)d_in[6];
    const float* dec_dense_b  = (const float*)d_in[7];
    const float* dec_tconv_w  = (const float*)d_in[8];
    const float* dec_tconv_b  = (const float*)d_in[9];
    float* out = (float*)d_out;

    const int N = in_sizes[0] / (NG * 64);                   // 4096
    const int CHUNKS = (N + NE * (NW - 1)) / NW + 1;         // 144
    int* sorted = (int*)d_ws;

    bin_kernel<<<1, 1024, 0, stream>>>(keys, N, CHUNKS * NW, sorted);
    ae_main<<<CHUNKS * NG, 256, 0, stream>>>(
        x, keys, conv_mask, enc_conv_w, enc_dense_w, enc_dense_b,
        dec_dense_w, dec_dense_b, dec_tconv_w, dec_tconv_b, sorted, out);
}